// Round 8
// baseline (13567.725 us; speedup 1.0000x reference)
//
#include <hip/hip_runtime.h>
#include <math.h>

// Problem constants (from reference)
#define T_STEPS 8192
#define INPUT   64
#define UNITS   1024
#define NMOD    4
#define LEAKY   0.9f

// Decomposition (validated R6/R7): 16 WGs per module; module = blockIdx%8
// (residues 0..3; 4..7 exit) so round-robin XCD dispatch puts each module's
// WGs on ONE XCD -> h exchange through that XCD's L2 (sc0 loads). Slow
// agent-scope (MALL) path backs it up for arbitrary placement.
//
// Transposed ownership (R7): lane l of EVERY wave owns column c = wgi*64+l.
// Wave w handles h-rows [64w,64w+64): polls those 64 packed entries, deposits
// in a wave-private LDS slice, re-reads as 16 uniform-address float4
// broadcasts, FMAs against 64 REGISTER-PINNED weights. Partials combine via
// double-buffered LDS; wave 0 finishes (bias+tanh+blend) and publishes.
#define K_WG        16
#define COLS_PER_WG 64
#define GRID        128
#define WGSIZE      1024

#define ENTRIES     (NMOD * UNITS)   // 4096 packed entries per buffer
// d_ws layout: slow[2][ENTRIES] then fast[2][ENTRIES], 64-bit {tag|value}.
#define WS_ULL      (4 * ENTRIES)

__global__ void init_ws_kernel(unsigned long long* __restrict__ b) {
    int i = blockIdx.x * blockDim.x + threadIdx.x;
    if (i < WS_ULL) b[i] = 0ULL;     // tag 0 < any t in 1..T
}

// tanh via exp2 + rcp: ~1e-6 rel err, correct saturation (verified R4).
__device__ __forceinline__ float tanh_fast(float x) {
    float e2x = __builtin_amdgcn_exp2f(x * 2.8853900817779268f); // 2*log2(e)
    float r   = __builtin_amdgcn_rcpf(e2x + 1.0f);
    return fmaf(-2.0f, r, 1.0f);
}

// L1-bypass (sc0) 8-byte load: served coherently from the LOCAL XCD's L2.
__device__ __forceinline__ unsigned long long load_l2(
        const unsigned long long* p) {
    unsigned long long v;
    asm volatile("global_load_dwordx2 %0, %1, off sc0\n\t"
                 "s_waitcnt vmcnt(0)"
                 : "=v"(v) : "v"(p) : "memory");
    return v;
}

__global__ __launch_bounds__(WGSIZE, 1)
void reservoir_persist(const float* __restrict__ u,
                       const float* __restrict__ kern,
                       const float* __restrict__ rec,
                       const float* __restrict__ bias,
                       float* __restrict__ out,
                       unsigned long long* __restrict__ slow,
                       unsigned long long* __restrict__ fast)
{
    const int wg  = blockIdx.x;
    const int res = wg & 7;
    if (res >= NMOD) return;             // residues 4..7 idle
    const int m   = res;                 // module 0..3
    const int wgi = wg >> 3;             // 0..15 within module

    const int tid  = threadIdx.x;
    const int w    = tid >> 6;           // wave 0..15  (row-slice owner)
    const int lane = tid & 63;

    const int c       = wgi * COLS_PER_WG + lane;  // my column (module-local)
    const int rowBase = 64 * w;                    // my wave's h-row slice

    __shared__ __align__(16) float h_slice[16][64]; // wave-private row slices
    __shared__ float part[2][16][64];               // DOUBLE-BUFFERED partials

    // ---- one-time preload of weights into registers ----
    const float* recm = rec + (size_t)m * UNITS * UNITS;
    float r[64];
#pragma unroll
    for (int j = 0; j < 16; ++j)
#pragma unroll
        for (int e = 0; e < 4; ++e)
            r[4 * j + e] = recm[(size_t)(rowBase + 4 * j + e) * UNITS + c];

    // input kernel slice: wave w folds u-rows [4w, 4w+4)
    const float* km = kern + (size_t)m * INPUT * UNITS;
    float k0 = km[(size_t)(4 * w + 0) * UNITS + c];
    float k1 = km[(size_t)(4 * w + 1) * UNITS + c];
    float k2 = km[(size_t)(4 * w + 2) * UNITS + c];
    float k3 = km[(size_t)(4 * w + 3) * UNITS + c];
    float bc = bias[m * UNITS + c];

    const float leak = LEAKY, omleak = 1.0f - LEAKY;

    h_slice[w][lane] = 0.0f;             // h_0 = 0 (wave-private slice)
    float hprev = 0.0f;                  // wave 0: my column's h state
    __syncthreads();

    const size_t modOff = (size_t)m * UNITS;

    // u quad for step 1 (uses u[0]); uniform per wave
    float4 uq = *reinterpret_cast<const float4*>(u + 4 * w);

    for (int t = 1; t <= T_STEPS; ++t) {
        const int pb = t & 1;

        // HARD PIN: loop-carried "+v" asm makes every weight an opaque
        // register-resident value -- the compiler cannot re-load it from
        // memory inside the loop (R6/R7: VGPR_Count 52/56 proved it was
        // sinking the loads; this forces residency).
#pragma unroll
        for (int j = 0; j < 64; ++j) asm("" : "+v"(r[j]));
        asm("" : "+v"(k0), "+v"(k1), "+v"(k2), "+v"(k3), "+v"(bc));

        // ---- FMA phase: rows [64w,64w+64) x my column, h via LDS broadcast
        const float4* __restrict__ hs4 =
            reinterpret_cast<const float4*>(h_slice[w]);
        float a0 = uq.x * k0, a1 = uq.y * k1, a2 = uq.z * k2, a3 = uq.w * k3;
#pragma unroll
        for (int j = 0; j < 16; ++j) {
            float4 hv4 = hs4[j];         // uniform address -> HW broadcast
            a0 = fmaf(r[4 * j + 0], hv4.x, a0);
            a1 = fmaf(r[4 * j + 1], hv4.y, a1);
            a2 = fmaf(r[4 * j + 2], hv4.z, a2);
            a3 = fmaf(r[4 * j + 3], hv4.w, a3);
        }
        part[pb][w][lane] = (a0 + a1) + (a2 + a3);
        __syncthreads();   // partials of step t visible; only barrier/step

        unsigned long long* fbW = fast + (size_t)pb * ENTRIES + modOff;
        unsigned long long* sbW = slow + (size_t)pb * ENTRIES + modOff;

        // ---- combine + publish (wave 0; lane l -> column c) ----
        // part[pb] reuse (next write at t+2) is race-free: wave w's
        // part[pb] write at t+2 requires its poll of (t+1)-publishes,
        // which requires every WG's (t+1)-publish, which requires that
        // WG's barrier at t+1, which requires ITS waves' t-polls, which
        // require THIS WG's t-publish, which follows these reads.
        if (w == 0) {
            float s0 = part[pb][0][lane] + part[pb][1][lane];
            float s1 = part[pb][2][lane] + part[pb][3][lane];
            float s2 = part[pb][4][lane] + part[pb][5][lane];
            float s3 = part[pb][6][lane] + part[pb][7][lane];
#pragma unroll
            for (int ww = 8; ww < 16; ww += 4) {
                s0 += part[pb][ww][lane];     s1 += part[pb][ww + 1][lane];
                s2 += part[pb][ww + 2][lane]; s3 += part[pb][ww + 3][lane];
            }
            float s = (s0 + s1) + (s2 + s3);
            float hn = omleak * hprev + leak * tanh_fast(s + bc);
            hprev = hn;
            unsigned long long pk =
                ((unsigned long long)(unsigned int)t << 32) |
                (unsigned long long)__float_as_uint(hn);
            // fast: plain store -> local XCD L2 (visible to sc0 loads there)
            __hip_atomic_store(&fbW[c], pk, __ATOMIC_RELAXED,
                               __HIP_MEMORY_SCOPE_WORKGROUP);
            // slow: agent store -> MALL (correct for any WG placement)
            __hip_atomic_store(&sbW[c], pk, __ATOMIC_RELAXED,
                               __HIP_MEMORY_SCOPE_AGENT);
        }

        // prefetch next u quad (latency overlaps the poll)
        if (t < T_STEPS)
            uq = *reinterpret_cast<const float4*>(u + (size_t)t * INPUT + 4 * w);

        // ---- poll my row slice: entry tid = 64w + lane ----
        unsigned long long v;
        for (;;) {
            v = load_l2(&fbW[tid]);
            if ((unsigned int)(v >> 32) == (unsigned int)t) break;
            v = __hip_atomic_load(&sbW[tid], __ATOMIC_RELAXED,
                                  __HIP_MEMORY_SCOPE_AGENT);
            if ((unsigned int)(v >> 32) == (unsigned int)t) break;
            __builtin_amdgcn_s_sleep(1);   // throttle the poll storm
        }
        const float hv = __uint_as_float((unsigned int)v);
        h_slice[w][lane] = hv;           // wave-private; in-wave ds ordering

        // one WG per module writes the coalesced output row (off crit path)
        if (wgi == 0)
            out[(size_t)(t - 1) * (NMOD * UNITS) + modOff + tid] = hv;
    }
}

extern "C" void kernel_launch(void* const* d_in, const int* in_sizes, int n_in,
                              void* d_out, int out_size, void* d_ws, size_t ws_size,
                              hipStream_t stream) {
    const float* u    = (const float*)d_in[0];  // [1, 8192, 64]
    const float* kern = (const float*)d_in[1];  // [4, 64, 1024]
    const float* rec  = (const float*)d_in[2];  // [4, 1024, 1024]
    const float* bias = (const float*)d_in[3];  // [4, 1024]
    float* out = (float*)d_out;                 // [1, 8192, 4096] f32

    unsigned long long* slow = (unsigned long long*)d_ws;              // 64 KB
    unsigned long long* fast = slow + 2 * ENTRIES;                     // 64 KB

    hipLaunchKernelGGL(init_ws_kernel, dim3((WS_ULL + 1023) / 1024), dim3(1024),
                       0, stream, slow);

    void* args[] = { (void*)&u, (void*)&kern, (void*)&rec, (void*)&bias,
                     (void*)&out, (void*)&slow, (void*)&fast };
    hipLaunchCooperativeKernel((const void*)reservoir_persist,
                               dim3(GRID), dim3(WGSIZE), args, 0, stream);
}